// Round 8
// baseline (1733.943 us; speedup 1.0000x reference)
//
#include <hip/hip_runtime.h>
#include <hip/hip_bf16.h>

// ScaleDotProduct attention fwd, MI355X gfx950.  B=2 H=16 S=2048 D=64.
// Dtypes (locked r5): Q/K/V f32, output f32, mask u8-or-i32 (runtime probe).
// Flash: one block (4 waves) per 64-row Q tile per (b,h).
//
// r18 = r13 compute (verified-correct, 2x PV rate, 0 bank conflicts) +
// EXPLICIT per-head pacing barrier to hold the L2-reuse equilibrium that
// r10 got implicitly from slow compute.  Quantified model: per XCD, 128
// resident blocks; same-head drift <= 1 iteration -> L2 demand 1MB/XCD <<
// 4MB -> full reuse (r10: FETCH 77MB).  r13's faster loop let drift grow ->
// collapse (197MB-1GB, r13-r16).  Pacing: after each 2-tile iteration,
// atomicAdd cnt[bh]; tid0 spins until all 32 same-head blocks arrive.
// ADVISORY ONLY: bounded spin (256 x s_sleep(1) ~7us) + permanent opt-out
// on timeout -> no deadlock possible; increments unconditional so an
// opted-out block can't starve peers.  Spin placed after next-tile DMA
// issue; next iteration's __syncthreads absorbs the wait (no new barrier).
// No setprio (m190 + desync suspect).  Identity grid mapping.
// Counters zeroed by prepass_all (stream-ordered before fa_fwd).
//
// Compute (r13-verified): sigma-permuted QK^T -> St subtile pairs concat
// into mfma_f32_16x16x32_f16 A-frags; PV = 8x K=32 mfma (half of r10's
// pipe time); V B-frags 8x ds_read_b128 conflict-free; K swizzle fswf(r)=
// (r&3)|((r>>3)&1)<<2, READ key = (ln&3)|(((ln>>2)&1)<<2) [sigma bit3 =
// ln bit2]; mask folded into St init (-512 bias, exp2 -> exact 0);
// cvt_pkrtz P-pack; wm pipelined 1 tile ahead; koff/voff precomputed.
// Layouts (m89/m120-verified): 16x16 C/D col=lane&15 row=quad*4+reg;
// 16x16x32 A [m=ln][k=quad*8+j], B [k=quad*8+j][n=ln].
// Fixed-max exp2-domain softmax: p=exp2(s*log2e/8); masked p=0; l==0 -> 0.

#define S_LEN 2048
#define D_DIM 64
#define BH    32
#define BM    64
#define BN    64
#define PST   72
#define QSCALE 0.1803368801f   // 0.125 * log2(e)

typedef __bf16    bf16_t;
typedef _Float16  f16_t;
typedef bf16_t bf16x8 __attribute__((ext_vector_type(8)));
typedef f16_t  f16x2  __attribute__((ext_vector_type(2)));
typedef f16_t  f16x4  __attribute__((ext_vector_type(4)));
typedef f16_t  f16x8  __attribute__((ext_vector_type(8)));
typedef float  f32x4  __attribute__((ext_vector_type(4)));
typedef unsigned char  u8;
typedef unsigned long long u64b;

__device__ __forceinline__ void load_lds16(const void* g, void* l) {
    __builtin_amdgcn_global_load_lds(
        (const __attribute__((address_space(1))) void*)g,
        (__attribute__((address_space(3))) void*)l, 16, 0, 0);
}

__device__ __forceinline__ f16x2 cvt_pk_f16(float a, float b) {
    return __builtin_bit_cast(f16x2, __builtin_amdgcn_cvt_pkrtz(a, b));
}

// swizzle group for K tiles (row bits 0,1,3 vary within one A-frag load)
__device__ __forceinline__ int fswf(int r) {
    return (r & 3) | (((r >> 3) & 1) << 2);
}

// ---- standalone mask pre-pass (fallback when only bm workspace fits)
__global__ __launch_bounds__(256)
void mask_to_bits(const unsigned* __restrict__ M, u64b* __restrict__ bm)
{
    const int t = threadIdx.x;
    unsigned p = M[(t * 8179) & ((1 << 21) - 1)];
    const int is_u8 = __syncthreads_or(p > 1u);
    const int id = blockIdx.x * 256 + t;   // u64 index; 131072 total
    u64b w = 0;
    if (is_u8) {
        const uint4* src = (const uint4*)((const u8*)M + (size_t)id * 64);
        #pragma unroll
        for (int g = 0; g < 4; ++g) {
            uint4 x = src[g];
            const unsigned dw[4] = {x.x, x.y, x.z, x.w};
            #pragma unroll
            for (int q = 0; q < 4; ++q) {
                const unsigned v = dw[q];
                const int base = g * 16 + q * 4;
                if (v & 0x000000FFu) w |= 1ull << (base + 0);
                if (v & 0x0000FF00u) w |= 1ull << (base + 1);
                if (v & 0x00FF0000u) w |= 1ull << (base + 2);
                if (v & 0xFF000000u) w |= 1ull << (base + 3);
            }
        }
    } else {
        const uint4* src = (const uint4*)(M + (size_t)id * 64);
        #pragma unroll
        for (int g = 0; g < 16; ++g) {
            uint4 x = src[g];
            if (x.x) w |= 1ull << (g * 4 + 0);
            if (x.y) w |= 1ull << (g * 4 + 1);
            if (x.z) w |= 1ull << (g * 4 + 2);
            if (x.w) w |= 1ull << (g * 4 + 3);
        }
    }
    bm[id] = w;
}

// ---- FUSED pre-pass: mask->bits + K->bf16 (fswf swizzle) + V->f16 images
// + pacing-counter zeroing.  512 blocks x 256 thr, one launch.
__global__ __launch_bounds__(256)
void prepass_all(const unsigned* __restrict__ M, u64b* __restrict__ bm,
                 const float* __restrict__ K, bf16_t* __restrict__ Kb,
                 const float* __restrict__ V, f16_t* __restrict__ Vt,
                 unsigned* __restrict__ cnt)
{
    const int t   = threadIdx.x;
    const int blk = blockIdx.x;           // 0..511

    if (cnt && blk == 0 && t < BH) cnt[t] = 0;   // pacing counters

    // -- mask dtype probe (256 shared samples -> uniform per-block verdict)
    unsigned p = M[(t * 8179) & ((1 << 21) - 1)];
    const int is_u8 = __syncthreads_or(p > 1u);

    // -- job 1: mask -> u64 bitmask (131072 words; 1 per thread)
    {
        const int id = blk * 256 + t;
        u64b w = 0;
        if (is_u8) {
            const uint4* src = (const uint4*)((const u8*)M + (size_t)id * 64);
            #pragma unroll
            for (int g = 0; g < 4; ++g) {
                uint4 x = src[g];
                const unsigned dw[4] = {x.x, x.y, x.z, x.w};
                #pragma unroll
                for (int q = 0; q < 4; ++q) {
                    const unsigned v = dw[q];
                    const int base = g * 16 + q * 4;
                    if (v & 0x000000FFu) w |= 1ull << (base + 0);
                    if (v & 0x0000FF00u) w |= 1ull << (base + 1);
                    if (v & 0x00FF0000u) w |= 1ull << (base + 2);
                    if (v & 0xFF000000u) w |= 1ull << (base + 3);
                }
            }
        } else {
            const uint4* src = (const uint4*)(M + (size_t)id * 64);
            #pragma unroll
            for (int g = 0; g < 16; ++g) {
                uint4 x = src[g];
                if (x.x) w |= 1ull << (g * 4 + 0);
                if (x.y) w |= 1ull << (g * 4 + 1);
                if (x.z) w |= 1ull << (g * 4 + 2);
                if (x.w) w |= 1ull << (g * 4 + 3);
            }
        }
        bm[id] = w;
    }

    // -- job 2: K -> bf16, 16B groups XOR-swizzled with fswf (r13 scheme);
    // 524288 vec8 chunks over 131072 threads = 4 each (grid-stride)
    #pragma unroll
    for (int j = 0; j < 4; ++j) {
        const size_t i = ((size_t)(blk * 256 + t) + (size_t)j * 131072) * 8;
        float4 a = *(const float4*)(K + i);
        float4 b = *(const float4*)(K + i + 4);
        bf16x8 w;
        w[0]=(bf16_t)a.x; w[1]=(bf16_t)a.y; w[2]=(bf16_t)a.z; w[3]=(bf16_t)a.w;
        w[4]=(bf16_t)b.x; w[5]=(bf16_t)b.y; w[6]=(bf16_t)b.z; w[7]=(bf16_t)b.w;
        const size_t r = i >> 6;
        const int    g = (int)((i & 63) >> 3);
        *(bf16x8*)(Kb + r * 64 + ((g ^ fswf((int)(r & 63))) * 8)) = w;
    }

    // -- job 3: V f32 [bh][s][d] -> Vt f16 tile-images
    // [bh][kbt][d][k_in64], 16B-group XOR swizzle (g^(d&7)).
    {
        __shared__ f16_t T[128][PST];
        const int sc = blk & 15;
        const int bh = blk >> 4;
        const float* Vh = V + ((size_t)bh * S_LEN + sc * 128) * D_DIM;
        #pragma unroll
        for (int it = 0; it < 4; ++it) {
            const int row = it * 32 + (t >> 3);
            const int c8  = (t & 7) * 8;
            float4 a = *(const float4*)(Vh + row * D_DIM + c8);
            float4 b = *(const float4*)(Vh + row * D_DIM + c8 + 4);
            f16_t* d = &T[row][c8];
            d[0]=(f16_t)a.x; d[1]=(f16_t)a.y; d[2]=(f16_t)a.z; d[3]=(f16_t)a.w;
            d[4]=(f16_t)b.x; d[5]=(f16_t)b.y; d[6]=(f16_t)b.z; d[7]=(f16_t)b.w;
        }
        __syncthreads();
        const int d = t >> 2;
        #pragma unroll
        for (int g = 0; g < 4; ++g) {
            const int s_off = (t & 3) * 32 + g * 8;       // s within 128-chunk
            const int kbt   = sc * 2 + (s_off >> 6);
            const int k_in  = s_off & 63;
            const int gk    = k_in >> 3;
            f16x4 w0, w1;
            #pragma unroll
            for (int j = 0; j < 4; ++j) { w0[j] = T[s_off + j][d]; w1[j] = T[s_off + 4 + j][d]; }
            f16_t* dst = Vt + (((size_t)bh * (S_LEN/BN) + kbt) * D_DIM + d) * 64
                            + ((gk ^ (d & 7)) * 8);
            *(f16x4*)dst = w0;
            *(f16x4*)(dst + 4) = w1;
        }
    }
}

__global__ __launch_bounds__(256, 4)
void fa_fwd(const float* __restrict__ Q, const float* __restrict__ K,
            const float* __restrict__ V, const void* __restrict__ M,
            const u64b* __restrict__ bm, const bf16_t* __restrict__ Kb,
            const f16_t* __restrict__ Vt, unsigned* __restrict__ cnt,
            float* __restrict__ O)
{
    __shared__ __align__(16) bf16_t KldsA[BN * D_DIM];
    __shared__ __align__(16) bf16_t KldsB[BN * D_DIM];
    __shared__ __align__(16) f16_t  VldsA[D_DIM * BN];
    __shared__ __align__(16) f16_t  VldsB[D_DIM * BN];

    const int tid  = threadIdx.x;
    const int wave = tid >> 6;
    const int lane = tid & 63;
    const int quad = lane >> 4;
    const int ln   = lane & 15;

    const int qt = blockIdx.x;   // q tile (0..31), identity mapping
    const int bh = blockIdx.y;   // b*16 + h
    const int b  = bh >> 4;
    const int qbase = qt * BM + wave * 16;

    const size_t head_off = (size_t)bh * S_LEN * D_DIM;
    const float* Qh = Q + head_off;
    const float* Kh = K + head_off;
    const float* Vh = V + head_off;
    const bf16_t* Kbh = Kb ? (Kb + head_off) : nullptr;
    const u8*  Mb8  = (const u8*)M  + (size_t)b * S_LEN * S_LEN;
    const int* Mb32 = (const int*)M + (size_t)b * S_LEN * S_LEN;

    int mask_is_u8 = 0;
    if (!bm) {   // fallback mask-dtype probe
        int probe = ((const int*)M)[(tid * 8179) & ((1 << 21) - 1)];
        mask_is_u8 = __syncthreads_or((unsigned)probe > 1u);
    }

    // ---- Q fragments (B-operand): f32 load, *QSCALE, cvt bf16 (once/block)
    bf16x8 qfrag[2];
    {
        const float* qrow = Qh + (size_t)(qbase + ln) * D_DIM;
        #pragma unroll
        for (int s = 0; s < 2; ++s) {
            float4 a = *(const float4*)(qrow + s * 32 + quad * 8);
            float4 c = *(const float4*)(qrow + s * 32 + quad * 8 + 4);
            bf16x8 w;
            w[0]=(bf16_t)(a.x*QSCALE); w[1]=(bf16_t)(a.y*QSCALE);
            w[2]=(bf16_t)(a.z*QSCALE); w[3]=(bf16_t)(a.w*QSCALE);
            w[4]=(bf16_t)(c.x*QSCALE); w[5]=(bf16_t)(c.y*QSCALE);
            w[6]=(bf16_t)(c.z*QSCALE); w[7]=(bf16_t)(c.w*QSCALE);
            qfrag[s] = w;
        }
    }

    f32x4 accO[4] = {{0.f,0.f,0.f,0.f},{0.f,0.f,0.f,0.f},
                     {0.f,0.f,0.f,0.f},{0.f,0.f,0.f,0.f}};
    float lpart = 0.f;

    // K rows sigma-permuted: t=2T+u -> lane ln loads key row
    // 32T + (ln>>2)*8 + 4u + (ln&3); read key = (ln&3)|(((ln>>2)&1)<<2)
    const int fswl = (ln & 3) | (((ln >> 2) & 1) << 2);
    const int xv   = ln & 7;
    int koff[2][4];
    #pragma unroll
    for (int s = 0; s < 2; ++s)
      #pragma unroll
      for (int T = 0; T < 2; ++T)
        #pragma unroll
        for (int u = 0; u < 2; ++u)
            koff[s][2*T+u] = (32*T + (ln >> 2) * 8 + 4*u + (ln & 3)) * D_DIM
                           + (((s*4 + quad) ^ fswl) * 8);
    int voff[2][4];
    #pragma unroll
    for (int T = 0; T < 2; ++T)
      #pragma unroll
      for (int dt = 0; dt < 4; ++dt)
            voff[T][dt] = (dt*16 + ln) * D_DIM + (((T*4 + quad) ^ xv) * 8);

    const size_t bmrow = ((size_t)b * S_LEN + qbase + ln) * 32;

    auto load_wm = [&](int kb) -> u64b {
        if (bm) return bm[bmrow + (kb >> 6)];
        u64b w = 0;
        if (mask_is_u8) {
            const u8* mp = Mb8 + (size_t)(qbase + ln) * S_LEN + kb;
            #pragma unroll
            for (int t2 = 0; t2 < 2; ++t2)
                #pragma unroll
                for (int j = 0; j < 8; ++j) {
                    const int k = t2*32 + quad*8 + j;
                    if (mp[k]) w |= 1ull << k;
                }
        } else {
            const int* mp = Mb32 + (size_t)(qbase + ln) * S_LEN + kb;
            #pragma unroll
            for (int t2 = 0; t2 < 2; ++t2)
                #pragma unroll
                for (int j = 0; j < 8; ++j) {
                    const int k = t2*32 + quad*8 + j;
                    if (mp[k]) w |= 1ull << k;
                }
        }
        return w;
    };

    auto prefetch = [&](int kb, bf16_t* Kl, f16_t* Vl) {
        const bf16_t* kt = Kbh + (size_t)kb * D_DIM;
        const f16_t*  vt = Vt + ((size_t)bh * (S_LEN/BN) + (kb >> 6)) * (BN * D_DIM);
        #pragma unroll
        for (int i = 0; i < 2; ++i) {
            const int c = wave + 4 * i;          // 1KB chunk id (8 per tile)
            load_lds16(kt + c * 512 + lane * 8, Kl + c * 512);
            load_lds16(vt + c * 512 + lane * 8, Vl + c * 512);
        }
    };

    auto compute_tile = [&](const bf16_t* Kl, const f16_t* Vl, u64b wm) {
        // mask in accumulator init: masked -> -512 bias; exp2 -> exact 0.
        f32x4 St[4];
        #pragma unroll
        for (int T = 0; T < 2; ++T)
          #pragma unroll
          for (int u = 0; u < 2; ++u) {
            const unsigned nib = (unsigned)(wm >> (T*32 + quad*8 + u*4)) & 0xFu;
            f32x4 iv;
            #pragma unroll
            for (int j = 0; j < 4; ++j)
                iv[j] = (nib & (1u << j)) ? -512.f : 0.f;
            St[2*T + u] = iv;
          }
        // S^T = K Q^T (exp2 domain)
        #pragma unroll
        for (int s = 0; s < 2; ++s)
          #pragma unroll
          for (int t = 0; t < 4; ++t) {
            bf16x8 ak = *(const bf16x8*)(Kl + koff[s][t]);
            St[t] = __builtin_amdgcn_mfma_f32_16x16x32_bf16(ak, qfrag[s], St[t], 0, 0, 0);
          }
        // p = exp2(s'); St[2T]||St[2T+1] -> 16x16x32_f16 A-frag
        #pragma unroll
        for (int T = 0; T < 2; ++T) {
            f16x2 h[4];
            #pragma unroll
            for (int u = 0; u < 2; ++u)
              #pragma unroll
              for (int jj = 0; jj < 2; ++jj) {
                const float e0 = __builtin_amdgcn_exp2f(St[2*T+u][2*jj]);
                const float e1 = __builtin_amdgcn_exp2f(St[2*T+u][2*jj+1]);
                lpart += e0 + e1;
                h[u*2+jj] = cvt_pk_f16(e0, e1);
              }
            const f16x8 pa = {h[0][0], h[0][1], h[1][0], h[1][1],
                              h[2][0], h[2][1], h[3][0], h[3][1]};
            // O += P V : 16x16x32 f16, B-frags = swizzled b128 from V^T tile
            #pragma unroll
            for (int dt = 0; dt < 4; ++dt) {
                f16x8 bv = *(const f16x8*)(Vl + voff[T][dt]);
                accO[dt] = __builtin_amdgcn_mfma_f32_16x16x32_f16(pa, bv, accO[dt], 0, 0, 0);
            }
        }
    };

    if (Kbh) {
        // ---- fast path: async DMA staging, double-buffered, 1 barrier/tile;
        // per-head pacing barrier at iteration end (advisory, bounded spin).
        bool paced = (cnt != nullptr);
        prefetch(0, KldsA, VldsA);
        u64b wmA = load_wm(0);
        for (int kb = 0; kb < S_LEN; kb += 2 * BN) {
            __syncthreads();                       // tile kb DMA landed
            u64b wmB = load_wm(kb + BN);
            if (kb + BN < S_LEN) prefetch(kb + BN, KldsB, VldsB);
            compute_tile(KldsA, VldsA, wmA);
            __syncthreads();                       // tile kb+BN DMA landed
            const int kn = (kb + 2*BN < S_LEN) ? (kb + 2*BN) : 0;
            wmA = load_wm(kn);
            if (kb + 2*BN < S_LEN) prefetch(kb + 2*BN, KldsA, VldsA);
            compute_tile(KldsB, VldsB, wmB);
            // pacing: next-tile DMA already in flight; next iteration's
            // __syncthreads makes waves wait on tid0's spin.
            if (cnt && tid == 0 && kb + 2*BN < S_LEN) {
                __hip_atomic_fetch_add(&cnt[bh], 1u, __ATOMIC_RELEASE,
                                       __HIP_MEMORY_SCOPE_AGENT);
                if (paced) {
                    const unsigned tgt = 32u * (unsigned)((kb >> 7) + 1);
                    int spins = 0;
                    while (__hip_atomic_load(&cnt[bh], __ATOMIC_ACQUIRE,
                                             __HIP_MEMORY_SCOPE_AGENT) < tgt) {
                        __builtin_amdgcn_s_sleep(1);
                        if (++spins > 256) { paced = false; break; }
                    }
                }
            }
        }
    } else {
        // ---- fallback: in-kernel cvt staging (swizzled), 2 barriers/tile
        const int srow = tid >> 2;
        const int sgrp = tid & 3;
        for (int kb = 0; kb < S_LEN; kb += BN) {
            __syncthreads();
            const float* kp = Kh + (size_t)(kb + srow) * D_DIM + sgrp * 16;
            #pragma unroll
            for (int h = 0; h < 2; ++h) {
                float4 a = *(const float4*)(kp + h * 8);
                float4 c = *(const float4*)(kp + h * 8 + 4);
                bf16x8 w;
                w[0]=(bf16_t)a.x; w[1]=(bf16_t)a.y; w[2]=(bf16_t)a.z; w[3]=(bf16_t)a.w;
                w[4]=(bf16_t)c.x; w[5]=(bf16_t)c.y; w[6]=(bf16_t)c.z; w[7]=(bf16_t)c.w;
                const int g = sgrp * 2 + h;
                *(bf16x8*)&KldsA[srow * D_DIM + ((g ^ fswf(srow)) * 8)] = w;
            }
            const float* vp = Vh + (size_t)(kb + srow) * D_DIM + sgrp * 16;
            float vv[16];
            #pragma unroll
            for (int g = 0; g < 4; ++g) {
                float4 a = *(const float4*)(vp + g * 4);
                vv[g*4+0]=a.x; vv[g*4+1]=a.y; vv[g*4+2]=a.z; vv[g*4+3]=a.w;
            }
            const int gk = srow >> 3;
            #pragma unroll
            for (int jj = 0; jj < 16; ++jj) {
                const int j = (jj + srow) & 15;            // bank derotation
                const int d = sgrp * 16 + j;
                VldsA[d * D_DIM + ((gk ^ (d & 7)) * 8) + (srow & 7)] = (f16_t)vv[j];
            }
            __syncthreads();
            compute_tile(KldsA, VldsA, load_wm(kb));
        }
    }

    // ---- epilogue: reduce l across quads (q=ln), gather per-row, O/l
    lpart += __shfl_xor(lpart, 16, 64);
    lpart += __shfl_xor(lpart, 32, 64);
    #pragma unroll
    for (int r = 0; r < 4; ++r) {
        const float lr  = __shfl(lpart, quad * 4 + r, 64);
        const float inv = (lr > 0.f) ? 1.f / lr : 0.f;
        float* orow = O + head_off + (size_t)(qbase + quad*4 + r) * D_DIM;
        #pragma unroll
        for (int dt = 0; dt < 4; ++dt)
            orow[16*dt + ln] = accO[dt][r] * inv;
    }
}

extern "C" void kernel_launch(void* const* d_in, const int* in_sizes, int n_in,
                              void* d_out, int out_size, void* d_ws, size_t ws_size,
                              hipStream_t stream) {
    (void)in_sizes; (void)n_in; (void)out_size;
    const float* Q = (const float*)d_in[0];
    const float* K = (const float*)d_in[1];
    const float* V = (const float*)d_in[2];
    const void*  M = d_in[3];
    float* O = (float*)d_out;

    const size_t bm_bytes = (size_t)2 * S_LEN * (S_LEN / 64) * 8;   // 1 MiB
    const size_t kv_elems = (size_t)BH * S_LEN * D_DIM;             // 4.19M
    const size_t need_all = bm_bytes + 2 * kv_elems * 2;            // +16.8MB

    u64b*   bm = (ws_size >= bm_bytes) ? (u64b*)d_ws : nullptr;
    bf16_t* Kb = nullptr; f16_t* Vt = nullptr; unsigned* cnt = nullptr;
    if (ws_size >= need_all) {
        Kb = (bf16_t*)((char*)d_ws + bm_bytes);
        Vt = (f16_t*)(Kb + kv_elems);
    }
    if (ws_size >= need_all + 4096)
        cnt = (unsigned*)((char*)d_ws + need_all);

    if (bm && Kb) {
        prepass_all<<<dim3(512), dim3(256), 0, stream>>>(
            (const unsigned*)M, bm, K, Kb, V, Vt, cnt);
    } else if (bm) {
        mask_to_bits<<<dim3(131072 / 256), dim3(256), 0, stream>>>(
            (const unsigned*)M, bm);
    }

    dim3 grid(S_LEN / BM, BH);
    fa_fwd<<<grid, dim3(256), 0, stream>>>(Q, K, V, M, bm, Kb, Vt, cnt, O);
}

// Round 9
// 177.361 us; speedup vs baseline: 9.7763x; 9.7763x over previous
//
#include <hip/hip_runtime.h>
#include <hip/hip_bf16.h>

// ScaleDotProduct attention fwd, MI355X gfx950.  B=2 H=16 S=2048 D=64.
// Dtypes (locked r5): Q/K/V f32, output f32, mask u8-or-i32 (runtime probe).
// Flash: one block (4 waves) per 64-row Q tile per (b,h).
//
// r19 = r17 VERBATIM (measured best: 176.0us total, fa_fwd 71.5us).
// Session findings (r11-r18), recorded for future passes:
//  * r10/r17 fa_fwd sits in a timing-self-synchronized equilibrium: 32
//    blocks/head sweep K/V in lockstep, L2 absorbs the 32x logical reuse
//    (FETCH 77MB ~= exactly-once).  The "surplus" per-tile compute (PV at
//    16x16x16 K=16 rate, serial mask tests) IS the pacing mechanism.
//  * Banking the compute savings fails every way tried:
//    - r13/r14: 2x-rate PV (K=32) + conflict-free reads, identical global
//      access -> desync -> FETCH 197-334MB, 185-189us.
//    - r15 (BM=128), r16 (exactly-once per block): 208us / 564us,
//      FETCH up to 1.06GB (TCC-side amplification never fully explained).
//    - r18: explicit per-head atomic pacing -> traffic FIXED (91MB,
//      theory confirmed) but AGENT-scope spin cost 60x the prize (1639us).
//  * XCD swizzles: lin%8 remap regressed 2.6x (r13); L3-fit regime ->
//    swizzle costs (guide m160 regime gate confirmed on this problem).
//  * Fused single-launch prepass (r17) saved ~6us vs 3 launches.
//  * ~80us of dur_us is harness-fixed (reset/memset train + replay gaps).
//
// r10 fa_fwd notes (verified 72us, FETCH 79MB):
//  * S^T orientation: QK^T computed as mfma(A=K,B=Q) -> C-layout lane holds
//    (q=ln, k=quad*4+r) == A-frag layout of mfma_f32_16x16x16f16 ->
//    exp2(S^T) feeds PV DIRECTLY in registers (no P LDS round-trip).
//  * V staged as f16; PV B-frags = swizzled ds_read_b64.
//  * Mask: one u64 bitmask load per lane (row q=ln); l = per-lane partial,
//    reduced once at epilogue (shfl_xor 16/32 + shfl gather).
//  * LDS 32KB -> 4 blocks/CU.
// Layouts (m89/m120-verified + canonical 16x16x16):
//   16x16 C/D: col=lane&15, row=quad*4+reg
//   16x16x32 A: [m=ln][k=quad*8+j]  B: [k=quad*8+j][n=ln]
//   16x16x16 A: [m=ln][k=quad*4+j]  B: [k=quad*4+j][n=ln]
// Fixed-max exp2-domain softmax (r7): p=exp2(s*log2e/8); masked p=0;
// l==0 -> 0 reproduces nan_to_num.

#define S_LEN 2048
#define D_DIM 64
#define BH    32
#define BM    64
#define BN    64
#define PST   72
#define QSCALE 0.1803368801f   // 0.125 * log2(e)

typedef __bf16    bf16_t;
typedef _Float16  f16_t;
typedef bf16_t bf16x8 __attribute__((ext_vector_type(8)));
typedef f16_t  f16x4  __attribute__((ext_vector_type(4)));
typedef float  f32x4  __attribute__((ext_vector_type(4)));
typedef unsigned char  u8;
typedef unsigned long long u64b;

__device__ __forceinline__ void load_lds16(const void* g, void* l) {
    __builtin_amdgcn_global_load_lds(
        (const __attribute__((address_space(1))) void*)g,
        (__attribute__((address_space(3))) void*)l, 16, 0, 0);
}

// ---- standalone mask pre-pass (fallback when only bm workspace fits)
__global__ __launch_bounds__(256)
void mask_to_bits(const unsigned* __restrict__ M, u64b* __restrict__ bm)
{
    const int t = threadIdx.x;
    unsigned p = M[(t * 8179) & ((1 << 21) - 1)];
    const int is_u8 = __syncthreads_or(p > 1u);
    const int id = blockIdx.x * 256 + t;   // u64 index; 131072 total
    u64b w = 0;
    if (is_u8) {
        const uint4* src = (const uint4*)((const u8*)M + (size_t)id * 64);
        #pragma unroll
        for (int g = 0; g < 4; ++g) {
            uint4 x = src[g];
            const unsigned dw[4] = {x.x, x.y, x.z, x.w};
            #pragma unroll
            for (int q = 0; q < 4; ++q) {
                const unsigned v = dw[q];
                const int base = g * 16 + q * 4;
                if (v & 0x000000FFu) w |= 1ull << (base + 0);
                if (v & 0x0000FF00u) w |= 1ull << (base + 1);
                if (v & 0x00FF0000u) w |= 1ull << (base + 2);
                if (v & 0xFF000000u) w |= 1ull << (base + 3);
            }
        }
    } else {
        const uint4* src = (const uint4*)(M + (size_t)id * 64);
        #pragma unroll
        for (int g = 0; g < 16; ++g) {
            uint4 x = src[g];
            if (x.x) w |= 1ull << (g * 4 + 0);
            if (x.y) w |= 1ull << (g * 4 + 1);
            if (x.z) w |= 1ull << (g * 4 + 2);
            if (x.w) w |= 1ull << (g * 4 + 3);
        }
    }
    bm[id] = w;
}

// ---- FUSED pre-pass: mask->bits + K->bf16 swizzled + V->f16 tile images.
// 512 blocks x 256 thr, one launch (replaces 3; kills 2 inter-launch gaps).
__global__ __launch_bounds__(256)
void prepass_all(const unsigned* __restrict__ M, u64b* __restrict__ bm,
                 const float* __restrict__ K, bf16_t* __restrict__ Kb,
                 const float* __restrict__ V, f16_t* __restrict__ Vt)
{
    const int t   = threadIdx.x;
    const int blk = blockIdx.x;           // 0..511

    // -- mask dtype probe (256 shared samples -> uniform per-block verdict)
    unsigned p = M[(t * 8179) & ((1 << 21) - 1)];
    const int is_u8 = __syncthreads_or(p > 1u);

    // -- job 1: mask -> u64 bitmask (131072 words; 1 per thread)
    {
        const int id = blk * 256 + t;
        u64b w = 0;
        if (is_u8) {
            const uint4* src = (const uint4*)((const u8*)M + (size_t)id * 64);
            #pragma unroll
            for (int g = 0; g < 4; ++g) {
                uint4 x = src[g];
                const unsigned dw[4] = {x.x, x.y, x.z, x.w};
                #pragma unroll
                for (int q = 0; q < 4; ++q) {
                    const unsigned v = dw[q];
                    const int base = g * 16 + q * 4;
                    if (v & 0x000000FFu) w |= 1ull << (base + 0);
                    if (v & 0x0000FF00u) w |= 1ull << (base + 1);
                    if (v & 0x00FF0000u) w |= 1ull << (base + 2);
                    if (v & 0xFF000000u) w |= 1ull << (base + 3);
                }
            }
        } else {
            const uint4* src = (const uint4*)(M + (size_t)id * 64);
            #pragma unroll
            for (int g = 0; g < 16; ++g) {
                uint4 x = src[g];
                if (x.x) w |= 1ull << (g * 4 + 0);
                if (x.y) w |= 1ull << (g * 4 + 1);
                if (x.z) w |= 1ull << (g * 4 + 2);
                if (x.w) w |= 1ull << (g * 4 + 3);
            }
        }
        bm[id] = w;
    }

    // -- job 2: K -> bf16, 16B groups XOR-swizzled (r10: g ^ (row&7));
    // 524288 vec8 chunks over 131072 threads = 4 each (grid-stride)
    #pragma unroll
    for (int j = 0; j < 4; ++j) {
        const size_t i = ((size_t)(blk * 256 + t) + (size_t)j * 131072) * 8;
        float4 a = *(const float4*)(K + i);
        float4 b = *(const float4*)(K + i + 4);
        bf16x8 w;
        w[0]=(bf16_t)a.x; w[1]=(bf16_t)a.y; w[2]=(bf16_t)a.z; w[3]=(bf16_t)a.w;
        w[4]=(bf16_t)b.x; w[5]=(bf16_t)b.y; w[6]=(bf16_t)b.z; w[7]=(bf16_t)b.w;
        const size_t r = i >> 6;
        const int    g = (int)((i & 63) >> 3);
        *(bf16x8*)(Kb + r * 64 + ((g ^ (int)(r & 7)) * 8)) = w;
    }

    // -- job 3: V f32 [bh][s][d] -> Vt f16 tile-images
    // [bh][kbt][d][k_in64], 16B-group XOR swizzle (g^(d&7)).
    // block -> (sc = blk&15, bh = blk>>4); identical body to r10 v_transpose.
    {
        __shared__ f16_t T[128][PST];
        const int sc = blk & 15;
        const int bh = blk >> 4;
        const float* Vh = V + ((size_t)bh * S_LEN + sc * 128) * D_DIM;
        #pragma unroll
        for (int it = 0; it < 4; ++it) {
            const int row = it * 32 + (t >> 3);
            const int c8  = (t & 7) * 8;
            float4 a = *(const float4*)(Vh + row * D_DIM + c8);
            float4 b = *(const float4*)(Vh + row * D_DIM + c8 + 4);
            f16_t* d = &T[row][c8];
            d[0]=(f16_t)a.x; d[1]=(f16_t)a.y; d[2]=(f16_t)a.z; d[3]=(f16_t)a.w;
            d[4]=(f16_t)b.x; d[5]=(f16_t)b.y; d[6]=(f16_t)b.z; d[7]=(f16_t)b.w;
        }
        __syncthreads();
        const int d = t >> 2;
        #pragma unroll
        for (int g = 0; g < 4; ++g) {
            const int s_off = (t & 3) * 32 + g * 8;       // s within 128-chunk
            const int kbt   = sc * 2 + (s_off >> 6);
            const int k_in  = s_off & 63;
            const int gk    = k_in >> 3;
            f16x4 w0, w1;
            #pragma unroll
            for (int j = 0; j < 4; ++j) { w0[j] = T[s_off + j][d]; w1[j] = T[s_off + 4 + j][d]; }
            f16_t* dst = Vt + (((size_t)bh * (S_LEN/BN) + kbt) * D_DIM + d) * 64
                            + ((gk ^ (d & 7)) * 8);
            *(f16x4*)dst = w0;
            *(f16x4*)(dst + 4) = w1;
        }
    }
}

__global__ __launch_bounds__(256, 4)
void fa_fwd(const float* __restrict__ Q, const float* __restrict__ K,
            const float* __restrict__ V, const void* __restrict__ M,
            const u64b* __restrict__ bm, const bf16_t* __restrict__ Kb,
            const f16_t* __restrict__ Vt, float* __restrict__ O)
{
    // separate symbols -> provably disjoint for alias analysis
    __shared__ __align__(16) bf16_t KldsA[BN * D_DIM];
    __shared__ __align__(16) bf16_t KldsB[BN * D_DIM];
    __shared__ __align__(16) f16_t  VldsA[D_DIM * BN];
    __shared__ __align__(16) f16_t  VldsB[D_DIM * BN];

    const int tid  = threadIdx.x;
    const int wave = tid >> 6;
    const int lane = tid & 63;
    const int quad = lane >> 4;
    const int ln   = lane & 15;

    const int qt = blockIdx.x;   // q tile (0..31)
    const int bh = blockIdx.y;   // b*16 + h
    const int b  = bh >> 4;
    const int qbase = qt * BM + wave * 16;

    const size_t head_off = (size_t)bh * S_LEN * D_DIM;
    const float* Qh = Q + head_off;
    const float* Kh = K + head_off;
    const float* Vh = V + head_off;
    const bf16_t* Kbh = Kb ? (Kb + head_off) : nullptr;
    const u8*  Mb8  = (const u8*)M  + (size_t)b * S_LEN * S_LEN;
    const int* Mb32 = (const int*)M + (size_t)b * S_LEN * S_LEN;

    int mask_is_u8 = 0;
    if (!bm) {   // fallback mask-dtype probe
        int probe = ((const int*)M)[(tid * 8179) & ((1 << 21) - 1)];
        mask_is_u8 = __syncthreads_or((unsigned)probe > 1u);
    }

    // ---- Q fragments (B-operand): f32 load, *QSCALE, cvt bf16 (once/block)
    bf16x8 qfrag[2];
    {
        const float* qrow = Qh + (size_t)(qbase + ln) * D_DIM;
        #pragma unroll
        for (int s = 0; s < 2; ++s) {
            float4 a = *(const float4*)(qrow + s * 32 + quad * 8);
            float4 c = *(const float4*)(qrow + s * 32 + quad * 8 + 4);
            bf16x8 w;
            w[0]=(bf16_t)(a.x*QSCALE); w[1]=(bf16_t)(a.y*QSCALE);
            w[2]=(bf16_t)(a.z*QSCALE); w[3]=(bf16_t)(a.w*QSCALE);
            w[4]=(bf16_t)(c.x*QSCALE); w[5]=(bf16_t)(c.y*QSCALE);
            w[6]=(bf16_t)(c.z*QSCALE); w[7]=(bf16_t)(c.w*QSCALE);
            qfrag[s] = w;
        }
    }

    f32x4 accO[4] = {{0.f,0.f,0.f,0.f},{0.f,0.f,0.f,0.f},
                     {0.f,0.f,0.f,0.f},{0.f,0.f,0.f,0.f}};
    float lpart = 0.f;   // per-lane partial l for q-row = ln

    const int xg = ln & 7;   // row-derived XOR for swizzled LDS reads
    const size_t bmrow = ((size_t)b * S_LEN + qbase + ln) * 32;

    auto load_wm = [&](int kb) -> u64b {
        if (bm) return bm[bmrow + (kb >> 6)];
        u64b w = 0;
        if (mask_is_u8) {
            const u8* mp = Mb8 + (size_t)(qbase + ln) * S_LEN + kb;
            #pragma unroll
            for (int t = 0; t < 4; ++t)
                #pragma unroll
                for (int j = 0; j < 4; ++j) {
                    const int k = t*16 + quad*4 + j;
                    if (mp[k]) w |= 1ull << k;
                }
        } else {
            const int* mp = Mb32 + (size_t)(qbase + ln) * S_LEN + kb;
            #pragma unroll
            for (int t = 0; t < 4; ++t)
                #pragma unroll
                for (int j = 0; j < 4; ++j) {
                    const int k = t*16 + quad*4 + j;
                    if (mp[k]) w |= 1ull << k;
                }
        }
        return w;
    };

    auto prefetch = [&](int kb, bf16_t* Kl, f16_t* Vl) {
        const bf16_t* kt = Kbh + (size_t)kb * D_DIM;
        const f16_t*  vt = Vt + ((size_t)bh * (S_LEN/BN) + (kb >> 6)) * (BN * D_DIM);
        #pragma unroll
        for (int i = 0; i < 2; ++i) {
            const int c = wave + 4 * i;          // 1KB chunk id (8 per tile)
            load_lds16(kt + c * 512 + lane * 8, Kl + c * 512);
            load_lds16(vt + c * 512 + lane * 8, Vl + c * 512);
        }
    };

    auto compute_tile = [&](const bf16_t* Kl, const f16_t* Vl, u64b wm) {
        // S^T = K Q^T (exp2 domain): mfma(A=K-frag, B=Q-frag)
        f32x4 St[4] = {{0.f,0.f,0.f,0.f},{0.f,0.f,0.f,0.f},
                       {0.f,0.f,0.f,0.f},{0.f,0.f,0.f,0.f}};
        __builtin_amdgcn_s_setprio(1);
        #pragma unroll
        for (int s = 0; s < 2; ++s) {
            #pragma unroll
            for (int t = 0; t < 4; ++t) {
                bf16x8 ak = *(const bf16x8*)
                    &Kl[(16*t + ln) * D_DIM + (((s*4 + quad) ^ xg) * 8)];
                St[t] = __builtin_amdgcn_mfma_f32_16x16x32_bf16(ak, qfrag[s], St[t], 0, 0, 0);
            }
        }
        __builtin_amdgcn_s_setprio(0);
        // p = exp2(s'), masked -> 0; pack to f16 A-frags IN REGISTERS
        f16x4 pa[4];
        #pragma unroll
        for (int t = 0; t < 4; ++t) {
            const unsigned nib = (unsigned)(wm >> (t*16 + quad*4)) & 0xFu;
            #pragma unroll
            for (int j = 0; j < 4; ++j) {
                const float p = (nib & (1u << j)) ? 0.f
                              : __builtin_amdgcn_exp2f(St[t][j]);
                lpart += p;
                pa[t][j] = (f16_t)p;
            }
        }
        // O += P V : 16x16x16 f16, B-frags = swizzled b64 from V^T tile
        __builtin_amdgcn_s_setprio(1);
        #pragma unroll
        for (int t = 0; t < 4; ++t) {
            #pragma unroll
            for (int dt = 0; dt < 4; ++dt) {
                const int g = 2*t + (quad >> 1);
                f16x4 bv = *(const f16x4*)
                    &Vl[(dt*16 + ln) * D_DIM + ((g ^ xg) * 8) + (quad & 1) * 4];
                accO[dt] = __builtin_amdgcn_mfma_f32_16x16x16f16(pa[t], bv, accO[dt], 0, 0, 0);
            }
        }
        __builtin_amdgcn_s_setprio(0);
    };

    if (Kbh) {
        // ---- fast path: async DMA staging, double-buffered, 1 barrier/tile
        prefetch(0, KldsA, VldsA);
        for (int kb = 0; kb < S_LEN; kb += 2 * BN) {
            __syncthreads();                       // tile kb DMA landed
            u64b wm = load_wm(kb);                 // issued before next DMA
            if (kb + BN < S_LEN) prefetch(kb + BN, KldsB, VldsB);
            compute_tile(KldsA, VldsA, wm);
            __syncthreads();                       // tile kb+BN DMA landed
            wm = load_wm(kb + BN);
            if (kb + 2*BN < S_LEN) prefetch(kb + 2*BN, KldsA, VldsA);
            compute_tile(KldsB, VldsB, wm);
        }
    } else {
        // ---- fallback: in-kernel cvt staging (swizzled), 2 barriers/tile
        const int srow = tid >> 2;
        const int sgrp = tid & 3;
        for (int kb = 0; kb < S_LEN; kb += BN) {
            __syncthreads();
            const float* kp = Kh + (size_t)(kb + srow) * D_DIM + sgrp * 16;
            #pragma unroll
            for (int h = 0; h < 2; ++h) {
                float4 a = *(const float4*)(kp + h * 8);
                float4 c = *(const float4*)(kp + h * 8 + 4);
                bf16x8 w;
                w[0]=(bf16_t)a.x; w[1]=(bf16_t)a.y; w[2]=(bf16_t)a.z; w[3]=(bf16_t)a.w;
                w[4]=(bf16_t)c.x; w[5]=(bf16_t)c.y; w[6]=(bf16_t)c.z; w[7]=(bf16_t)c.w;
                const int g = sgrp * 2 + h;
                *(bf16x8*)&KldsA[srow * D_DIM + ((g ^ (srow & 7)) * 8)] = w;
            }
            const float* vp = Vh + (size_t)(kb + srow) * D_DIM + sgrp * 16;
            float vv[16];
            #pragma unroll
            for (int g = 0; g < 4; ++g) {
                float4 a = *(const float4*)(vp + g * 4);
                vv[g*4+0]=a.x; vv[g*4+1]=a.y; vv[g*4+2]=a.z; vv[g*4+3]=a.w;
            }
            const int gk = srow >> 3;
            #pragma unroll
            for (int jj = 0; jj < 16; ++jj) {
                const int j = (jj + srow) & 15;            // bank derotation
                const int d = sgrp * 16 + j;
                VldsA[d * D_DIM + ((gk ^ (d & 7)) * 8) + (srow & 7)] = (f16_t)vv[j];
            }
            __syncthreads();
            compute_tile(KldsA, VldsA, load_wm(kb));
        }
    }

    // ---- epilogue: reduce l across quads (q=ln), gather per-row, O/l
    lpart += __shfl_xor(lpart, 16, 64);
    lpart += __shfl_xor(lpart, 32, 64);
    #pragma unroll
    for (int r = 0; r < 4; ++r) {
        const float lr  = __shfl(lpart, quad * 4 + r, 64);  // lane ln==q==quad*4+r
        const float inv = (lr > 0.f) ? 1.f / lr : 0.f;
        float* orow = O + head_off + (size_t)(qbase + quad*4 + r) * D_DIM;
        #pragma unroll
        for (int dt = 0; dt < 4; ++dt)
            orow[16*dt + ln] = accO[dt][r] * inv;
    }
}

extern "C" void kernel_launch(void* const* d_in, const int* in_sizes, int n_in,
                              void* d_out, int out_size, void* d_ws, size_t ws_size,
                              hipStream_t stream) {
    (void)in_sizes; (void)n_in; (void)out_size;
    const float* Q = (const float*)d_in[0];
    const float* K = (const float*)d_in[1];
    const float* V = (const float*)d_in[2];
    const void*  M = d_in[3];
    float* O = (float*)d_out;

    const size_t bm_bytes = (size_t)2 * S_LEN * (S_LEN / 64) * 8;   // 1 MiB
    const size_t kv_elems = (size_t)BH * S_LEN * D_DIM;             // 4.19M
    const size_t need_all = bm_bytes + 2 * kv_elems * 2;            // +16.8MB

    u64b*   bm = (ws_size >= bm_bytes) ? (u64b*)d_ws : nullptr;
    bf16_t* Kb = nullptr; f16_t* Vt = nullptr;
    if (ws_size >= need_all) {
        Kb = (bf16_t*)((char*)d_ws + bm_bytes);
        Vt = (f16_t*)(Kb + kv_elems);
    }

    if (bm && Kb) {
        // single fused pre-pass launch (replaces 3)
        prepass_all<<<dim3(512), dim3(256), 0, stream>>>(
            (const unsigned*)M, bm, K, Kb, V, Vt);
    } else if (bm) {
        mask_to_bits<<<dim3(131072 / 256), dim3(256), 0, stream>>>(
            (const unsigned*)M, bm);
    }

    dim3 grid(S_LEN / BM, BH);
    fa_fwd<<<grid, dim3(256), 0, stream>>>(Q, K, V, M, bm, Kb, Vt, O);
}